// Round 1
// baseline (391.301 us; speedup 1.0000x reference)
//
#include <hip/hip_runtime.h>

typedef __bf16 bf16_t;
typedef __bf16 bf16x4 __attribute__((ext_vector_type(4)));
typedef __bf16 bf16x8 __attribute__((ext_vector_type(8)));
typedef float f32x4 __attribute__((ext_vector_type(4)));

#define LXS 264  // padded LDS row stride in bf16 elems (256 + 8): breaks 32-way bank conflict, keeps 16B align

// ============ prep: pack weights into bf16 MFMA B-fragment-major layout ============
// B-frag for (nt, kt): lane l, elem j -> B[k][n], k = kt*32 + (l>>4)*8 + j, n = nt*16 + (l&15)
// packed[((nt*8 + kt)*64 + l)*8 + j]
__global__ __launch_bounds__(256) void k_prep(
    const float* __restrict__ Wg, const float* __restrict__ Wo,
    const float* __restrict__ Wk, const float* __restrict__ Wv,
    bf16_t* __restrict__ WgP, bf16_t* __restrict__ WoP, bf16_t* __restrict__ WKVP)
{
    int id = blockIdx.x * 256 + threadIdx.x;
    if (id < 65536) {
        int j = id & 7, l = (id >> 3) & 63, kt = (id >> 9) & 7, nt = id >> 12;
        int k = kt * 32 + (l >> 4) * 8 + j;
        int n = nt * 16 + (l & 15);
        WgP[id] = (bf16_t)Wg[k * 256 + n];
    } else if (id < 131072) {
        int t = id - 65536;
        int j = t & 7, l = (t >> 3) & 63, kt = (t >> 9) & 7, nt = t >> 12;
        int k = kt * 32 + (l >> 4) * 8 + j;
        int n = nt * 16 + (l & 15);
        WoP[t] = (bf16_t)Wo[k * 256 + n];
    } else if (id < 147456) {
        int t = id - 131072;
        int j = t & 7, l = (t >> 3) & 63, kt = (t >> 9) & 7, nt = t >> 12;  // nt 0..3
        int k = kt * 32 + (l >> 4) * 8 + j;
        int n = nt * 16 + (l & 15);
        WKVP[t] = (bf16_t)(n < 32 ? Wk[k * 32 + n] : Wv[k * 32 + (n - 32)]);
    }
}

// ============ kA: LayerNorm -> x_ln (bf16) ; K|V = x_ln @ [Wk|Wv] via MFMA ============
// 64 rows/block, 4 waves; wave-per-row LN; then wave w computes 16 output cols (nt=w) x 64 rows
__global__ __launch_bounds__(256) void kA(
    const float* __restrict__ msa, const float* __restrict__ gamma, const float* __restrict__ beta,
    bf16_t* __restrict__ xln, bf16_t* __restrict__ kv, const bf16_t* __restrict__ WKVP)
{
    __shared__ __align__(16) bf16_t lx[64 * LXS];
    int tid = threadIdx.x;
    int lane = tid & 63, w = tid >> 6;
    int l15 = lane & 15, l4 = lane >> 4;
    int rowbase = blockIdx.x * 64;

    float4 g4 = ((const float4*)gamma)[lane];
    float4 b4 = ((const float4*)beta)[lane];

    for (int t = 0; t < 16; ++t) {
        int rl = w * 16 + t;
        int r = rowbase + rl;
        float4 x = ((const float4*)msa)[r * 64 + lane];
        float s  = x.x + x.y + x.z + x.w;
        float ss = x.x*x.x + x.y*x.y + x.z*x.z + x.w*x.w;
        #pragma unroll
        for (int m = 32; m; m >>= 1) { s += __shfl_xor(s, m, 64); ss += __shfl_xor(ss, m, 64); }
        float mu = s * (1.0f / 256.0f);
        float var = ss * (1.0f / 256.0f) - mu * mu;
        float rs = rsqrtf(var + 1e-5f);
        float4 y;
        y.x = (x.x - mu) * rs * g4.x + b4.x;
        y.y = (x.y - mu) * rs * g4.y + b4.y;
        y.z = (x.z - mu) * rs * g4.z + b4.z;
        y.w = (x.w - mu) * rs * g4.w + b4.w;
        bf16x4 xv;
        xv[0] = (bf16_t)y.x; xv[1] = (bf16_t)y.y; xv[2] = (bf16_t)y.z; xv[3] = (bf16_t)y.w;
        *(bf16x4*)(xln + (size_t)r * 256 + lane * 4) = xv;
        *(bf16x4*)(lx + rl * LXS + lane * 4) = xv;
    }
    __syncthreads();

    // MFMA: A = lx (64x256), B = WKVP (256x64), wave w -> cols [w*16, w*16+16)
    f32x4 acc[4];
    #pragma unroll
    for (int rt = 0; rt < 4; ++rt) acc[rt] = (f32x4){0.f, 0.f, 0.f, 0.f};
    #pragma unroll
    for (int kt = 0; kt < 8; ++kt) {
        bf16x8 b = *(const bf16x8*)(WKVP + ((w * 8 + kt) * 64 + lane) * 8);
        #pragma unroll
        for (int rt = 0; rt < 4; ++rt) {
            bf16x8 a = *(bf16x8*)(lx + (rt * 16 + l15) * LXS + kt * 32 + l4 * 8);
            acc[rt] = __builtin_amdgcn_mfma_f32_16x16x32_bf16(a, b, acc[rt], 0, 0, 0);
        }
    }
    #pragma unroll
    for (int rt = 0; rt < 4; ++rt) {
        #pragma unroll
        for (int j = 0; j < 4; ++j) {
            int row = rt * 16 + l4 * 4 + j;
            int r = rowbase + row;
            kv[(size_t)r * 64 + w * 16 + l15] = (bf16_t)acc[rt][j];
        }
    }
}

// ============ kB: masked column-sum of x_ln over s -> pooled Q (fp32) ============
// one block per i; Q[i][e] = (sum_s m*xln) @ Wq * 1/(clip(sum m,1)*sqrt(32))
__global__ __launch_bounds__(256) void kB(
    const bf16_t* __restrict__ xln, const float* __restrict__ mask,
    const float* __restrict__ Wq, float* __restrict__ Q)
{
    int i = blockIdx.x, tid = threadIdx.x;
    int qrt = tid >> 6, c0 = (tid & 63) * 4;
    __shared__ float part[4][256];
    __shared__ float msl[4];
    __shared__ float xs[256];
    float a0 = 0, a1 = 0, a2 = 0, a3 = 0, ms = 0;
    for (int k = 0; k < 128; ++k) {
        int t = k * 4 + qrt;
        float mv = mask[t * 512 + i];
        bf16x4 v = *(const bf16x4*)(xln + ((size_t)t * 512 + i) * 256 + c0);
        a0 += mv * (float)v[0]; a1 += mv * (float)v[1];
        a2 += mv * (float)v[2]; a3 += mv * (float)v[3];
        ms += mv;
    }
    part[qrt][c0] = a0; part[qrt][c0 + 1] = a1; part[qrt][c0 + 2] = a2; part[qrt][c0 + 3] = a3;
    if ((tid & 63) == 0) msl[qrt] = ms;
    __syncthreads();
    xs[tid] = part[0][tid] + part[1][tid] + part[2][tid] + part[3][tid];
    __syncthreads();
    float denom = fmaxf(msl[0] + msl[1] + msl[2] + msl[3], 1.0f);
    float scale = 1.0f / (denom * 5.656854249492381f);  // sqrt(32)
    float q = 0;
    for (int c = 0; c < 256; ++c) q += xs[c] * Wq[c * 256 + tid];
    Q[i * 256 + tid] = q * scale;
}

// ============ kC: per-column-i attention: scores -> softmax(t) -> weighted = attn @ V ============
__global__ __launch_bounds__(256) void kC(
    const bf16_t* __restrict__ kv, const float* __restrict__ mask,
    const float* __restrict__ Q, float* __restrict__ wout)
{
    int i = blockIdx.x, tid = threadIdx.x;
    __shared__ __align__(16) bf16_t kbuf[512 * 32];  // 32KB: K rows, then reused for V
    __shared__ float sc[512 * 8];                    // 16KB scores [t][h]
    __shared__ float qq[256];
    __shared__ float mk[512];
    __shared__ float rcp[8];

    qq[tid] = Q[i * 256 + tid];
    mk[tid] = mask[tid * 512 + i];
    mk[tid + 256] = mask[(tid + 256) * 512 + i];

    // stage K: row t = 64B = 4 x uint4 (first half of 128B KV row)
    for (int it = 0; it < 8; ++it) {
        int idx = it * 256 + tid; int t = idx >> 2; int q = idx & 3;
        ((uint4*)kbuf)[t * 4 + q] = ((const uint4*)kv)[((size_t)t * 512 + i) * 8 + q];
    }
    __syncthreads();

    // scores[t][h] = Q[h,:].K[t,:] (Q pre-scaled) + mask bias
    for (int it = 0; it < 16; ++it) {
        int idx = it * 256 + tid; int t = idx >> 3; int h = idx & 7;
        float a = 0;
        #pragma unroll 8
        for (int d = 0; d < 32; ++d) a += qq[h * 32 + d] * (float)kbuf[t * 32 + d];
        sc[t * 8 + h] = a - (1.0f - mk[t]) * 1e9f;
    }
    __syncthreads();

    // softmax over t for each h: 8 groups x 32 lanes
    {
        int h = tid >> 5, l = tid & 31;
        float m = -1e30f;
        for (int k = 0; k < 16; ++k) m = fmaxf(m, sc[(l + 32 * k) * 8 + h]);
        #pragma unroll
        for (int off = 16; off; off >>= 1) m = fmaxf(m, __shfl_xor(m, off, 64));
        float s = 0;
        for (int k = 0; k < 16; ++k) {
            int idx = (l + 32 * k) * 8 + h;
            float p = __expf(sc[idx] - m);
            sc[idx] = p; s += p;
        }
        #pragma unroll
        for (int off = 16; off; off >>= 1) s += __shfl_xor(s, off, 64);
        if (l == 0) rcp[h] = 1.0f / s;
    }
    // stage V into kbuf (no one reads K anymore after the barrier above)
    for (int it = 0; it < 8; ++it) {
        int idx = it * 256 + tid; int t = idx >> 2; int q = idx & 3;
        ((uint4*)kbuf)[t * 4 + q] = ((const uint4*)kv)[((size_t)t * 512 + i) * 8 + 4 + q];
    }
    __syncthreads();

    // weighted[h,d] = sum_t p[t,h] * V[t,d] * rcp[h]
    {
        int h = tid >> 5, d = tid & 31;
        float acc = 0;
        for (int t = 0; t < 512; ++t) acc += sc[t * 8 + h] * (float)kbuf[t * 32 + d];
        wout[i * 256 + tid] = acc * rcp[h];
    }
}

// ============ kD: G = sigmoid(xln@Wg + bg); gated = G*weighted[i]; out = gated@Wo + bo, *mask ====
// 64 rows/block, 4 waves; wave w owns output cols [w*64, w*64+64) (4 ct tiles), all 64 rows
__global__ __launch_bounds__(256) void kD(
    const bf16_t* __restrict__ xln, const bf16_t* __restrict__ WgP, const bf16_t* __restrict__ WoP,
    const float* __restrict__ bg, const float* __restrict__ bo,
    const float* __restrict__ weighted, const float* __restrict__ mask, float* __restrict__ out)
{
    __shared__ __align__(16) bf16_t lx[64 * LXS];  // xln tile, then reused for gated tile
    int tid = threadIdx.x;
    int lane = tid & 63, w = tid >> 6;
    int l15 = lane & 15, l4 = lane >> 4;
    int rowbase = blockIdx.x * 64;

    // stage xln tile: 64 rows x 512B
    for (int it = 0; it < 8; ++it) {
        int idx = it * 256 + tid; int row = idx >> 5; int q = idx & 31;
        uint4 v = ((const uint4*)xln)[((size_t)rowbase + row) * 32 + q];
        *(uint4*)(lx + row * LXS + q * 8) = v;
    }
    __syncthreads();

    f32x4 acc[4][4];  // [rt][ctl]
    #pragma unroll
    for (int rt = 0; rt < 4; ++rt)
        #pragma unroll
        for (int ctl = 0; ctl < 4; ++ctl) acc[rt][ctl] = (f32x4){0.f, 0.f, 0.f, 0.f};

    // stage 1: T = xln @ Wg
    #pragma unroll
    for (int kt = 0; kt < 8; ++kt) {
        bf16x8 a[4];
        #pragma unroll
        for (int rt = 0; rt < 4; ++rt) a[rt] = *(bf16x8*)(lx + (rt * 16 + l15) * LXS + kt * 32 + l4 * 8);
        #pragma unroll
        for (int ctl = 0; ctl < 4; ++ctl) {
            int ct = w * 4 + ctl;
            bf16x8 b = *(const bf16x8*)(WgP + ((ct * 8 + kt) * 64 + lane) * 8);
            #pragma unroll
            for (int rt = 0; rt < 4; ++rt)
                acc[rt][ctl] = __builtin_amdgcn_mfma_f32_16x16x32_bf16(a[rt], b, acc[rt][ctl], 0, 0, 0);
        }
    }
    __syncthreads();  // all waves done reading lx

    // epilogue 1: sigmoid gate * weighted -> gated (bf16) into lx
    #pragma unroll
    for (int ctl = 0; ctl < 4; ++ctl) {
        int col = (w * 4 + ctl) * 16 + l15;
        float bgv = bg[col];
        #pragma unroll
        for (int rt = 0; rt < 4; ++rt) {
            #pragma unroll
            for (int j = 0; j < 4; ++j) {
                int row = rt * 16 + l4 * 4 + j;
                int i = (rowbase + row) & 511;
                float t = acc[rt][ctl][j] + bgv;
                float gv = 1.0f / (1.0f + __expf(-t));
                float gg = gv * weighted[i * 256 + col];
                lx[row * LXS + col] = (bf16_t)gg;
            }
        }
    }
    __syncthreads();

    // stage 2: out = gated @ Wo
    #pragma unroll
    for (int rt = 0; rt < 4; ++rt)
        #pragma unroll
        for (int ctl = 0; ctl < 4; ++ctl) acc[rt][ctl] = (f32x4){0.f, 0.f, 0.f, 0.f};
    #pragma unroll
    for (int kt = 0; kt < 8; ++kt) {
        bf16x8 a[4];
        #pragma unroll
        for (int rt = 0; rt < 4; ++rt) a[rt] = *(bf16x8*)(lx + (rt * 16 + l15) * LXS + kt * 32 + l4 * 8);
        #pragma unroll
        for (int ctl = 0; ctl < 4; ++ctl) {
            int ct = w * 4 + ctl;
            bf16x8 b = *(const bf16x8*)(WoP + ((ct * 8 + kt) * 64 + lane) * 8);
            #pragma unroll
            for (int rt = 0; rt < 4; ++rt)
                acc[rt][ctl] = __builtin_amdgcn_mfma_f32_16x16x32_bf16(a[rt], b, acc[rt][ctl], 0, 0, 0);
        }
    }
    // epilogue 2: + bo, * mask, store f32
    #pragma unroll
    for (int ctl = 0; ctl < 4; ++ctl) {
        int col = (w * 4 + ctl) * 16 + l15;
        float bov = bo[col];
        #pragma unroll
        for (int rt = 0; rt < 4; ++rt) {
            #pragma unroll
            for (int j = 0; j < 4; ++j) {
                int row = rt * 16 + l4 * 4 + j;
                int r = rowbase + row;
                float mv = mask[r];
                out[(size_t)r * 256 + col] = (acc[rt][ctl][j] + bov) * mv;
            }
        }
    }
}

extern "C" void kernel_launch(void* const* d_in, const int* in_sizes, int n_in,
                              void* d_out, int out_size, void* d_ws, size_t ws_size,
                              hipStream_t stream) {
    const float* msa   = (const float*)d_in[0];
    const float* mask  = (const float*)d_in[1];
    const float* gamma = (const float*)d_in[2];
    const float* beta  = (const float*)d_in[3];
    const float* Wq    = (const float*)d_in[4];
    const float* Wk    = (const float*)d_in[5];
    const float* Wv    = (const float*)d_in[6];
    const float* Wg    = (const float*)d_in[7];
    const float* bg    = (const float*)d_in[8];
    const float* Wo    = (const float*)d_in[9];
    const float* bo    = (const float*)d_in[10];
    float* out = (float*)d_out;

    char* ws = (char*)d_ws;
    bf16_t* xln  = (bf16_t*)(ws);                     // 262144*256 bf16 = 128 MB
    bf16_t* kv   = (bf16_t*)(ws + 134217728);         // 262144*64 bf16 = 32 MB
    float*  Qp   = (float*)(ws + 167772160);          // 512*256 f32
    float*  wgt  = (float*)(ws + 168296448);          // 512*256 f32
    bf16_t* WgP  = (bf16_t*)(ws + 168820736);         // 65536 bf16
    bf16_t* WoP  = (bf16_t*)(ws + 168951808);         // 65536 bf16
    bf16_t* WKVP = (bf16_t*)(ws + 169082880);         // 16384 bf16

    k_prep<<<576, 256, 0, stream>>>(Wg, Wo, Wk, Wv, WgP, WoP, WKVP);
    kA<<<4096, 256, 0, stream>>>(msa, gamma, beta, xln, kv, WKVP);
    kB<<<512, 256, 0, stream>>>(xln, mask, Wq, Qp);
    kC<<<512, 256, 0, stream>>>(kv, mask, Qp, wgt);
    kD<<<4096, 256, 0, stream>>>(xln, WgP, WoP, bg, bo, wgt, mask, out);
}

// Round 2
// 372.084 us; speedup vs baseline: 1.0516x; 1.0516x over previous
//
#include <hip/hip_runtime.h>

typedef __bf16 bf16_t;
typedef __bf16 bf16x4 __attribute__((ext_vector_type(4)));
typedef __bf16 bf16x8 __attribute__((ext_vector_type(8)));
typedef float f32x4 __attribute__((ext_vector_type(4)));

#define LXS 264  // padded LDS row stride (kA only)

#define GLOAD_LDS16(gsrc, ldst) \
    __builtin_amdgcn_global_load_lds((__attribute__((address_space(1))) void*)(gsrc), \
                                     (__attribute__((address_space(3))) void*)(ldst), 16, 0, 0)

// ============ prep: pack weights into bf16 MFMA B-fragment-major layout ============
// B-frag for (nt, kt): lane l, elem j -> B[k][n], k = kt*32 + (l>>4)*8 + j, n = nt*16 + (l&15)
__global__ __launch_bounds__(256) void k_prep(
    const float* __restrict__ Wg, const float* __restrict__ Wo,
    const float* __restrict__ Wk, const float* __restrict__ Wv,
    bf16_t* __restrict__ WgP, bf16_t* __restrict__ WoP, bf16_t* __restrict__ WKVP)
{
    int id = blockIdx.x * 256 + threadIdx.x;
    if (id < 65536) {
        int j = id & 7, l = (id >> 3) & 63, kt = (id >> 9) & 7, nt = id >> 12;
        int k = kt * 32 + (l >> 4) * 8 + j;
        int n = nt * 16 + (l & 15);
        WgP[id] = (bf16_t)Wg[k * 256 + n];
    } else if (id < 131072) {
        int t = id - 65536;
        int j = t & 7, l = (t >> 3) & 63, kt = (t >> 9) & 7, nt = t >> 12;
        int k = kt * 32 + (l >> 4) * 8 + j;
        int n = nt * 16 + (l & 15);
        WoP[t] = (bf16_t)Wo[k * 256 + n];
    } else if (id < 147456) {
        int t = id - 131072;
        int j = t & 7, l = (t >> 3) & 63, kt = (t >> 9) & 7, nt = t >> 12;  // nt 0..3
        int k = kt * 32 + (l >> 4) * 8 + j;
        int n = nt * 16 + (l & 15);
        WKVP[t] = (bf16_t)(n < 32 ? Wk[k * 32 + n] : Wv[k * 32 + (n - 32)]);
    }
}

// ============ kA: LayerNorm -> x_ln (bf16) ; K|V = x_ln @ [Wk|Wv] via MFMA ============
__global__ __launch_bounds__(256) void kA(
    const float* __restrict__ msa, const float* __restrict__ gamma, const float* __restrict__ beta,
    bf16_t* __restrict__ xln, bf16_t* __restrict__ kv, const bf16_t* __restrict__ WKVP)
{
    __shared__ __align__(16) bf16_t lx[64 * LXS];
    int tid = threadIdx.x;
    int lane = tid & 63, w = tid >> 6;
    int l15 = lane & 15, l4 = lane >> 4;
    int rowbase = blockIdx.x * 64;

    float4 g4 = ((const float4*)gamma)[lane];
    float4 b4 = ((const float4*)beta)[lane];

    for (int t = 0; t < 16; ++t) {
        int rl = w * 16 + t;
        int r = rowbase + rl;
        float4 x = ((const float4*)msa)[r * 64 + lane];
        float s  = x.x + x.y + x.z + x.w;
        float ss = x.x*x.x + x.y*x.y + x.z*x.z + x.w*x.w;
        #pragma unroll
        for (int m = 32; m; m >>= 1) { s += __shfl_xor(s, m, 64); ss += __shfl_xor(ss, m, 64); }
        float mu = s * (1.0f / 256.0f);
        float var = ss * (1.0f / 256.0f) - mu * mu;
        float rs = rsqrtf(var + 1e-5f);
        float4 y;
        y.x = (x.x - mu) * rs * g4.x + b4.x;
        y.y = (x.y - mu) * rs * g4.y + b4.y;
        y.z = (x.z - mu) * rs * g4.z + b4.z;
        y.w = (x.w - mu) * rs * g4.w + b4.w;
        bf16x4 xv;
        xv[0] = (bf16_t)y.x; xv[1] = (bf16_t)y.y; xv[2] = (bf16_t)y.z; xv[3] = (bf16_t)y.w;
        *(bf16x4*)(xln + (size_t)r * 256 + lane * 4) = xv;
        *(bf16x4*)(lx + rl * LXS + lane * 4) = xv;
    }
    __syncthreads();

    f32x4 acc[4];
    #pragma unroll
    for (int rt = 0; rt < 4; ++rt) acc[rt] = (f32x4){0.f, 0.f, 0.f, 0.f};
    #pragma unroll
    for (int kt = 0; kt < 8; ++kt) {
        bf16x8 b = *(const bf16x8*)(WKVP + ((w * 8 + kt) * 64 + lane) * 8);
        #pragma unroll
        for (int rt = 0; rt < 4; ++rt) {
            bf16x8 a = *(bf16x8*)(lx + (rt * 16 + l15) * LXS + kt * 32 + l4 * 8);
            acc[rt] = __builtin_amdgcn_mfma_f32_16x16x32_bf16(a, b, acc[rt], 0, 0, 0);
        }
    }
    #pragma unroll
    for (int rt = 0; rt < 4; ++rt) {
        #pragma unroll
        for (int j = 0; j < 4; ++j) {
            int row = rt * 16 + l4 * 4 + j;
            int r = rowbase + row;
            kv[(size_t)r * 64 + w * 16 + l15] = (bf16_t)acc[rt][j];
        }
    }
}

// ============ kB: masked column-sum of x_ln over s -> pooled Q (fp32) ============
__global__ __launch_bounds__(256) void kB(
    const bf16_t* __restrict__ xln, const float* __restrict__ mask,
    const float* __restrict__ Wq, float* __restrict__ Q)
{
    int i = blockIdx.x, tid = threadIdx.x;
    int qrt = tid >> 6, c0 = (tid & 63) * 4;
    __shared__ float part[4][256];
    __shared__ float msl[4];
    __shared__ float xs[256];
    float a0 = 0, a1 = 0, a2 = 0, a3 = 0, ms = 0;
    for (int k = 0; k < 128; ++k) {
        int t = k * 4 + qrt;
        float mv = mask[t * 512 + i];
        bf16x4 v = *(const bf16x4*)(xln + ((size_t)t * 512 + i) * 256 + c0);
        a0 += mv * (float)v[0]; a1 += mv * (float)v[1];
        a2 += mv * (float)v[2]; a3 += mv * (float)v[3];
        ms += mv;
    }
    part[qrt][c0] = a0; part[qrt][c0 + 1] = a1; part[qrt][c0 + 2] = a2; part[qrt][c0 + 3] = a3;
    if ((tid & 63) == 0) msl[qrt] = ms;
    __syncthreads();
    xs[tid] = part[0][tid] + part[1][tid] + part[2][tid] + part[3][tid];
    __syncthreads();
    float denom = fmaxf(msl[0] + msl[1] + msl[2] + msl[3], 1.0f);
    float scale = 1.0f / (denom * 5.656854249492381f);  // sqrt(32)
    float q = 0;
    for (int c = 0; c < 256; ++c) q += xs[c] * Wq[c * 256 + tid];
    Q[i * 256 + tid] = q * scale;
}

// ============ kC: per-column-i attention: scores -> softmax(t) -> weighted = attn @ V ============
__global__ __launch_bounds__(256) void kC(
    const bf16_t* __restrict__ kv, const float* __restrict__ mask,
    const float* __restrict__ Q, float* __restrict__ wout)
{
    int i = blockIdx.x, tid = threadIdx.x;
    __shared__ __align__(16) bf16_t kbuf[512 * 32];
    __shared__ float sc[512 * 8];
    __shared__ float qq[256];
    __shared__ float mk[512];
    __shared__ float rcp[8];

    qq[tid] = Q[i * 256 + tid];
    mk[tid] = mask[tid * 512 + i];
    mk[tid + 256] = mask[(tid + 256) * 512 + i];

    for (int it = 0; it < 8; ++it) {
        int idx = it * 256 + tid; int t = idx >> 2; int q = idx & 3;
        ((uint4*)kbuf)[t * 4 + q] = ((const uint4*)kv)[((size_t)t * 512 + i) * 8 + q];
    }
    __syncthreads();

    for (int it = 0; it < 16; ++it) {
        int idx = it * 256 + tid; int t = idx >> 3; int h = idx & 7;
        float a = 0;
        #pragma unroll 8
        for (int d = 0; d < 32; ++d) a += qq[h * 32 + d] * (float)kbuf[t * 32 + d];
        sc[t * 8 + h] = a - (1.0f - mk[t]) * 1e9f;
    }
    __syncthreads();

    {
        int h = tid >> 5, l = tid & 31;
        float m = -1e30f;
        for (int k = 0; k < 16; ++k) m = fmaxf(m, sc[(l + 32 * k) * 8 + h]);
        #pragma unroll
        for (int off = 16; off; off >>= 1) m = fmaxf(m, __shfl_xor(m, off, 64));
        float s = 0;
        for (int k = 0; k < 16; ++k) {
            int idx = (l + 32 * k) * 8 + h;
            float p = __expf(sc[idx] - m);
            sc[idx] = p; s += p;
        }
        #pragma unroll
        for (int off = 16; off; off >>= 1) s += __shfl_xor(s, off, 64);
        if (l == 0) rcp[h] = 1.0f / s;
    }
    for (int it = 0; it < 8; ++it) {
        int idx = it * 256 + tid; int t = idx >> 2; int q = idx & 3;
        ((uint4*)kbuf)[t * 4 + q] = ((const uint4*)kv)[((size_t)t * 512 + i) * 8 + 4 + q];
    }
    __syncthreads();

    {
        int h = tid >> 5, d = tid & 31;
        float acc = 0;
        for (int t = 0; t < 512; ++t) acc += sc[t * 8 + h] * (float)kbuf[t * 32 + d];
        wout[i * 256 + tid] = acc * rcp[h];
    }
}

// ============ kD: 8 waves, 128 rows/block, swizzled linear LDS + global_load_lds staging ====
// wave w: rows [ (w>>2)*64, +64 ), cols [ (w&3)*64, +64 )
// LDS layout: lx[row][256] bf16, granule-swizzled: 16B granule g of row r lives at g^(r&7)
__global__ __launch_bounds__(512, 4) void kD(
    const bf16_t* __restrict__ xln, const bf16_t* __restrict__ WgP, const bf16_t* __restrict__ WoP,
    const float* __restrict__ bg, const float* __restrict__ bo,
    const float* __restrict__ weighted, const float* __restrict__ mask, float* __restrict__ out)
{
    __shared__ __align__(16) bf16_t lx[128 * 256];  // 64 KB, xln tile then gated tile
    int tid = threadIdx.x;
    int lane = tid & 63, w = tid >> 6;
    int l15 = lane & 15, l4 = lane >> 4;
    int h = w >> 2, q = w & 3;
    int rbase = h * 64;              // wave's local row base
    int rowbase = blockIdx.x * 128;  // block's global row base

    // stage xln tile: 8 x (1KB per wave) via global_load_lds, inverse-swizzled source
    const bf16_t* srcBase = xln + (size_t)rowbase * 256;
    #pragma unroll
    for (int c = 0; c < 8; ++c) {
        int idx = (w * 8 + c) * 1024 + lane * 16;  // byte offset in linear tile
        int row = idx >> 9;
        int g = (idx >> 4) & 31;
        int gs = g ^ (row & 7);
        GLOAD_LDS16(srcBase + row * 256 + gs * 8, lx + (w * 8 + c) * 512);
    }
    __syncthreads();

    int swb = l15 & 7;  // (r&7) is l15&7 for all A-frag rows (rbase, rt*16 are mult of 8)

    f32x4 acc[4][4];
    #pragma unroll
    for (int rt = 0; rt < 4; ++rt)
        #pragma unroll
        for (int ctl = 0; ctl < 4; ++ctl) acc[rt][ctl] = (f32x4){0.f, 0.f, 0.f, 0.f};

    // stage 1: T = xln @ Wg
    #pragma unroll
    for (int kt = 0; kt < 8; ++kt) {
        bf16x8 a[4];
        #pragma unroll
        for (int rt = 0; rt < 4; ++rt) {
            int r = rbase + rt * 16 + l15;
            a[rt] = *(bf16x8*)(lx + r * 256 + ((kt * 4 + l4) ^ swb) * 8);
        }
        #pragma unroll
        for (int ctl = 0; ctl < 4; ++ctl) {
            int ct = q * 4 + ctl;
            bf16x8 b = *(const bf16x8*)(WgP + ((ct * 8 + kt) * 64 + lane) * 8);
            #pragma unroll
            for (int rt = 0; rt < 4; ++rt)
                acc[rt][ctl] = __builtin_amdgcn_mfma_f32_16x16x32_bf16(a[rt], b, acc[rt][ctl], 0, 0, 0);
        }
    }
    __syncthreads();  // all stage-1 A-reads complete before overwrite

    // epilogue 1: gated = sigmoid(T + bg) * weighted -> back into lx (swizzled scalar writes)
    #pragma unroll
    for (int ctl = 0; ctl < 4; ++ctl) {
        int col = (q * 4 + ctl) * 16 + l15;
        float bgv = bg[col];
        int g0 = col >> 3, c7 = col & 7;
        #pragma unroll
        for (int rt = 0; rt < 4; ++rt) {
            #pragma unroll
            for (int j = 0; j < 4; ++j) {
                int row = rbase + rt * 16 + l4 * 4 + j;
                int i = (rowbase + row) & 511;
                float t = acc[rt][ctl][j] + bgv;
                float gv = 1.0f / (1.0f + __expf(-t));
                float gg = gv * weighted[i * 256 + col];
                lx[row * 256 + ((g0 ^ (row & 7)) << 3) + c7] = (bf16_t)gg;
            }
        }
    }
    __syncthreads();

    // stage 2: out = gated @ Wo
    #pragma unroll
    for (int rt = 0; rt < 4; ++rt)
        #pragma unroll
        for (int ctl = 0; ctl < 4; ++ctl) acc[rt][ctl] = (f32x4){0.f, 0.f, 0.f, 0.f};
    #pragma unroll
    for (int kt = 0; kt < 8; ++kt) {
        bf16x8 a[4];
        #pragma unroll
        for (int rt = 0; rt < 4; ++rt) {
            int r = rbase + rt * 16 + l15;
            a[rt] = *(bf16x8*)(lx + r * 256 + ((kt * 4 + l4) ^ swb) * 8);
        }
        #pragma unroll
        for (int ctl = 0; ctl < 4; ++ctl) {
            int ct = q * 4 + ctl;
            bf16x8 b = *(const bf16x8*)(WoP + ((ct * 8 + kt) * 64 + lane) * 8);
            #pragma unroll
            for (int rt = 0; rt < 4; ++rt)
                acc[rt][ctl] = __builtin_amdgcn_mfma_f32_16x16x32_bf16(a[rt], b, acc[rt][ctl], 0, 0, 0);
        }
    }
    // epilogue 2: + bo, * mask, store f32
    #pragma unroll
    for (int ctl = 0; ctl < 4; ++ctl) {
        int col = (q * 4 + ctl) * 16 + l15;
        float bov = bo[col];
        #pragma unroll
        for (int rt = 0; rt < 4; ++rt) {
            #pragma unroll
            for (int j = 0; j < 4; ++j) {
                int row = rbase + rt * 16 + l4 * 4 + j;
                int r = rowbase + row;
                out[(size_t)r * 256 + col] = (acc[rt][ctl][j] + bov) * mask[r];
            }
        }
    }
}

extern "C" void kernel_launch(void* const* d_in, const int* in_sizes, int n_in,
                              void* d_out, int out_size, void* d_ws, size_t ws_size,
                              hipStream_t stream) {
    const float* msa   = (const float*)d_in[0];
    const float* mask  = (const float*)d_in[1];
    const float* gamma = (const float*)d_in[2];
    const float* beta  = (const float*)d_in[3];
    const float* Wq    = (const float*)d_in[4];
    const float* Wk    = (const float*)d_in[5];
    const float* Wv    = (const float*)d_in[6];
    const float* Wg    = (const float*)d_in[7];
    const float* bg    = (const float*)d_in[8];
    const float* Wo    = (const float*)d_in[9];
    const float* bo    = (const float*)d_in[10];
    float* out = (float*)d_out;

    char* ws = (char*)d_ws;
    bf16_t* xln  = (bf16_t*)(ws);                     // 128 MB
    bf16_t* kv   = (bf16_t*)(ws + 134217728);         // 32 MB
    float*  Qp   = (float*)(ws + 167772160);
    float*  wgt  = (float*)(ws + 168296448);
    bf16_t* WgP  = (bf16_t*)(ws + 168820736);
    bf16_t* WoP  = (bf16_t*)(ws + 168951808);
    bf16_t* WKVP = (bf16_t*)(ws + 169082880);

    k_prep<<<576, 256, 0, stream>>>(Wg, Wo, Wk, Wv, WgP, WoP, WKVP);
    kA<<<4096, 256, 0, stream>>>(msa, gamma, beta, xln, kv, WKVP);
    kB<<<512, 256, 0, stream>>>(xln, mask, Wq, Qp);
    kC<<<512, 256, 0, stream>>>(kv, mask, Qp, wgt);
    kD<<<2048, 512, 0, stream>>>(xln, WgP, WoP, bg, bo, wgt, mask, out);
}

// Round 3
// 301.816 us; speedup vs baseline: 1.2965x; 1.2328x over previous
//
#include <hip/hip_runtime.h>

typedef __bf16 bf16_t;
typedef __bf16 bf16x4 __attribute__((ext_vector_type(4)));
typedef __bf16 bf16x8 __attribute__((ext_vector_type(8)));
typedef float f32x4 __attribute__((ext_vector_type(4)));

#define LXS 264  // padded LDS row stride (kA only)

#define GLOAD_LDS16(gsrc, ldst) \
    __builtin_amdgcn_global_load_lds((__attribute__((address_space(1))) void*)(gsrc), \
                                     (__attribute__((address_space(3))) void*)(ldst), 16, 0, 0)

// ============ prep: pack weights into bf16 MFMA B-fragment-major layout ============
// B-frag for (nt, kt): lane l, elem j -> B[k][n], k = kt*32 + (l>>4)*8 + j, n = nt*16 + (l&15)
__global__ __launch_bounds__(256) void k_prep(
    const float* __restrict__ Wg, const float* __restrict__ Wo,
    const float* __restrict__ Wk, const float* __restrict__ Wv,
    bf16_t* __restrict__ WgP, bf16_t* __restrict__ WoP, bf16_t* __restrict__ WKVP)
{
    int id = blockIdx.x * 256 + threadIdx.x;
    if (id < 65536) {
        int j = id & 7, l = (id >> 3) & 63, kt = (id >> 9) & 7, nt = id >> 12;
        int k = kt * 32 + (l >> 4) * 8 + j;
        int n = nt * 16 + (l & 15);
        WgP[id] = (bf16_t)Wg[k * 256 + n];
    } else if (id < 131072) {
        int t = id - 65536;
        int j = t & 7, l = (t >> 3) & 63, kt = (t >> 9) & 7, nt = t >> 12;
        int k = kt * 32 + (l >> 4) * 8 + j;
        int n = nt * 16 + (l & 15);
        WoP[t] = (bf16_t)Wo[k * 256 + n];
    } else if (id < 147456) {
        int t = id - 131072;
        int j = t & 7, l = (t >> 3) & 63, kt = (t >> 9) & 7, nt = t >> 12;  // nt 0..3
        int k = kt * 32 + (l >> 4) * 8 + j;
        int n = nt * 16 + (l & 15);
        WKVP[t] = (bf16_t)(n < 32 ? Wk[k * 32 + n] : Wv[k * 32 + (n - 32)]);
    }
}

// ============ kA: LN -> x_ln (bf16); K|V via MFMA; fused masked column-partials for Q-pool ====
// block b: i = b&511, s-chunk = b>>9 (64 s values). Rows r = (s0+t)*512 + i.
__global__ __launch_bounds__(256) void kA(
    const float* __restrict__ msa, const float* __restrict__ mask,
    const float* __restrict__ gamma, const float* __restrict__ beta,
    bf16_t* __restrict__ xln, bf16_t* __restrict__ kv, const bf16_t* __restrict__ WKVP,
    float* __restrict__ Qpart, float* __restrict__ Qcnt)
{
    __shared__ __align__(16) bf16_t lx[64 * LXS];
    __shared__ float pp[4][256];
    __shared__ float cw[4];
    int tid = threadIdx.x;
    int lane = tid & 63, w = tid >> 6;
    int l15 = lane & 15, l4 = lane >> 4;
    int i = blockIdx.x & 511;
    int schunk = blockIdx.x >> 9;
    int s0 = schunk * 64;

    float4 g4 = ((const float4*)gamma)[lane];
    float4 b4 = ((const float4*)beta)[lane];

    // preload the wave's 8 B-fragments (K|V weights) into regs
    bf16x8 bfr[8];
    #pragma unroll
    for (int kt = 0; kt < 8; ++kt)
        bfr[kt] = *(const bf16x8*)(WKVP + ((w * 8 + kt) * 64 + lane) * 8);

    float p0 = 0, p1 = 0, p2 = 0, p3 = 0, pc = 0;
    for (int t = 0; t < 16; ++t) {
        int rl = w * 16 + t;
        size_t r = (size_t)(s0 + rl) * 512 + i;
        float4 x = ((const float4*)(msa + r * 256))[lane];
        float mv = mask[r];
        float s  = x.x + x.y + x.z + x.w;
        float ss = x.x*x.x + x.y*x.y + x.z*x.z + x.w*x.w;
        #pragma unroll
        for (int m = 32; m; m >>= 1) { s += __shfl_xor(s, m, 64); ss += __shfl_xor(ss, m, 64); }
        float mu = s * (1.0f / 256.0f);
        float var = ss * (1.0f / 256.0f) - mu * mu;
        float rs = rsqrtf(var + 1e-5f);
        float4 y;
        y.x = (x.x - mu) * rs * g4.x + b4.x;
        y.y = (x.y - mu) * rs * g4.y + b4.y;
        y.z = (x.z - mu) * rs * g4.z + b4.z;
        y.w = (x.w - mu) * rs * g4.w + b4.w;
        bf16x4 xv;
        xv[0] = (bf16_t)y.x; xv[1] = (bf16_t)y.y; xv[2] = (bf16_t)y.z; xv[3] = (bf16_t)y.w;
        *(bf16x4*)(xln + r * 256 + lane * 4) = xv;
        *(bf16x4*)(lx + rl * LXS + lane * 4) = xv;
        p0 += mv * y.x; p1 += mv * y.y; p2 += mv * y.z; p3 += mv * y.w;
        pc += mv;
    }
    *(float4*)&pp[w][lane * 4] = (float4){p0, p1, p2, p3};
    if (lane == 0) cw[w] = pc;
    __syncthreads();

    // Q-pool partials (one slot per (schunk, i) -> written exactly once, no init needed)
    {
        float qs = pp[0][tid] + pp[1][tid] + pp[2][tid] + pp[3][tid];
        Qpart[((size_t)schunk * 512 + i) * 256 + tid] = qs;
        if (tid == 0) Qcnt[schunk * 512 + i] = cw[0] + cw[1] + cw[2] + cw[3];
    }

    // MFMA: A = lx (64x256), B = bfr (regs), wave w -> cols [w*16, +16)
    f32x4 acc[4];
    #pragma unroll
    for (int rt = 0; rt < 4; ++rt) acc[rt] = (f32x4){0.f, 0.f, 0.f, 0.f};
    #pragma unroll
    for (int kt = 0; kt < 8; ++kt) {
        #pragma unroll
        for (int rt = 0; rt < 4; ++rt) {
            bf16x8 a = *(bf16x8*)(lx + (rt * 16 + l15) * LXS + kt * 32 + l4 * 8);
            acc[rt] = __builtin_amdgcn_mfma_f32_16x16x32_bf16(a, bfr[kt], acc[rt], 0, 0, 0);
        }
    }
    #pragma unroll
    for (int rt = 0; rt < 4; ++rt) {
        #pragma unroll
        for (int j = 0; j < 4; ++j) {
            int row = rt * 16 + l4 * 4 + j;
            size_t r = (size_t)(s0 + row) * 512 + i;
            kv[r * 64 + w * 16 + l15] = (bf16_t)acc[rt][j];
        }
    }
}

// ============ kB: finish Q-pool: sum 8 partials, tiny GEMM with Wq ============
__global__ __launch_bounds__(256) void kB(
    const float* __restrict__ Qpart, const float* __restrict__ Qcnt,
    const float* __restrict__ Wq, float* __restrict__ Q)
{
    int i = blockIdx.x, tid = threadIdx.x;
    __shared__ float xs[256];
    float s = 0;
    #pragma unroll
    for (int ch = 0; ch < 8; ++ch) s += Qpart[((size_t)ch * 512 + i) * 256 + tid];
    xs[tid] = s;
    float cnt = 0;
    #pragma unroll
    for (int ch = 0; ch < 8; ++ch) cnt += Qcnt[ch * 512 + i];
    __syncthreads();
    float scale = 1.0f / (fmaxf(cnt, 1.0f) * 5.656854249492381f);  // sqrt(32)
    float q = 0;
    for (int c = 0; c < 256; ++c) q += xs[c] * Wq[c * 256 + tid];
    Q[i * 256 + tid] = q * scale;
}

// ============ kC: per-column-i attention: scores -> softmax(t) -> weighted = attn @ V ============
__global__ __launch_bounds__(256) void kC(
    const bf16_t* __restrict__ kv, const float* __restrict__ mask,
    const float* __restrict__ Q, float* __restrict__ wout)
{
    int i = blockIdx.x, tid = threadIdx.x;
    __shared__ __align__(16) bf16_t kbuf[512 * 32];
    __shared__ float sc[512 * 8];
    __shared__ float qq[256];
    __shared__ float mk[512];
    __shared__ float rcp[8];

    qq[tid] = Q[i * 256 + tid];
    mk[tid] = mask[tid * 512 + i];
    mk[tid + 256] = mask[(tid + 256) * 512 + i];

    for (int it = 0; it < 8; ++it) {
        int idx = it * 256 + tid; int t = idx >> 2; int q = idx & 3;
        ((uint4*)kbuf)[t * 4 + q] = ((const uint4*)kv)[((size_t)t * 512 + i) * 8 + q];
    }
    __syncthreads();

    for (int it = 0; it < 16; ++it) {
        int idx = it * 256 + tid; int t = idx >> 3; int h = idx & 7;
        float a = 0;
        #pragma unroll 8
        for (int d = 0; d < 32; ++d) a += qq[h * 32 + d] * (float)kbuf[t * 32 + d];
        sc[t * 8 + h] = a - (1.0f - mk[t]) * 1e9f;
    }
    __syncthreads();

    {
        int h = tid >> 5, l = tid & 31;
        float m = -1e30f;
        for (int k = 0; k < 16; ++k) m = fmaxf(m, sc[(l + 32 * k) * 8 + h]);
        #pragma unroll
        for (int off = 16; off; off >>= 1) m = fmaxf(m, __shfl_xor(m, off, 64));
        float s = 0;
        for (int k = 0; k < 16; ++k) {
            int idx = (l + 32 * k) * 8 + h;
            float p = __expf(sc[idx] - m);
            sc[idx] = p; s += p;
        }
        #pragma unroll
        for (int off = 16; off; off >>= 1) s += __shfl_xor(s, off, 64);
        if (l == 0) rcp[h] = 1.0f / s;
    }
    for (int it = 0; it < 8; ++it) {
        int idx = it * 256 + tid; int t = idx >> 2; int q = idx & 3;
        ((uint4*)kbuf)[t * 4 + q] = ((const uint4*)kv)[((size_t)t * 512 + i) * 8 + 4 + q];
    }
    __syncthreads();

    {
        int h = tid >> 5, d = tid & 31;
        float acc = 0;
        for (int t = 0; t < 512; ++t) acc += sc[t * 8 + h] * (float)kbuf[t * 32 + d];
        wout[i * 256 + tid] = acc * rcp[h];
    }
}

// ============ kD: 4 waves, 64 rows/block; B-frags preloaded to regs; swizzled LDS A ====
// wave q: all 64 rows x cols [q*64, +64)
__global__ __launch_bounds__(256, 2) void kD(
    const bf16_t* __restrict__ xln, const bf16_t* __restrict__ WgP, const bf16_t* __restrict__ WoP,
    const float* __restrict__ bg, const float* __restrict__ bo,
    const float* __restrict__ weighted, const float* __restrict__ mask, float* __restrict__ out)
{
    __shared__ __align__(16) bf16_t lx[64 * 256];  // 32 KB, xln tile then gated tile
    int tid = threadIdx.x;
    int lane = tid & 63, q = tid >> 6;
    int l15 = lane & 15, l4 = lane >> 4;
    int rowbase = blockIdx.x * 64;

    // stage xln tile (32 KB) via global_load_lds, inverse-swizzled source
    const bf16_t* srcBase = xln + (size_t)rowbase * 256;
    #pragma unroll
    for (int c = 0; c < 8; ++c) {
        int idx = (c * 256 + tid) * 16;  // byte offset in linear tile
        int row = idx >> 9;
        int g = (idx >> 4) & 31;
        int gs = g ^ (row & 7);
        GLOAD_LDS16(srcBase + row * 256 + gs * 8, lx + c * 2048 + q * 512);
    }

    // preload stage-1 B fragments (Wg): 32 x bf16x8 = 128 VGPRs
    bf16x8 bfr[4][8];
    #pragma unroll
    for (int ctl = 0; ctl < 4; ++ctl)
        #pragma unroll
        for (int kt = 0; kt < 8; ++kt)
            bfr[ctl][kt] = *(const bf16x8*)(WgP + (((q * 4 + ctl) * 8 + kt) * 64 + lane) * 8);
    __syncthreads();

    int swb = l15 & 7;

    f32x4 acc[4][4];
    #pragma unroll
    for (int rt = 0; rt < 4; ++rt)
        #pragma unroll
        for (int ctl = 0; ctl < 4; ++ctl) acc[rt][ctl] = (f32x4){0.f, 0.f, 0.f, 0.f};

    // stage 1: T = xln @ Wg  (pure LDS + reg)
    #pragma unroll
    for (int kt = 0; kt < 8; ++kt) {
        bf16x8 a[4];
        #pragma unroll
        for (int rt = 0; rt < 4; ++rt)
            a[rt] = *(bf16x8*)(lx + (rt * 16 + l15) * 256 + ((kt * 4 + l4) ^ swb) * 8);
        #pragma unroll
        for (int ctl = 0; ctl < 4; ++ctl)
            #pragma unroll
            for (int rt = 0; rt < 4; ++rt)
                acc[rt][ctl] = __builtin_amdgcn_mfma_f32_16x16x32_bf16(a[rt], bfr[ctl][kt], acc[rt][ctl], 0, 0, 0);
    }
    __syncthreads();  // stage-1 A-reads complete before epi1 overwrites lx

    // issue stage-2 B preload (Wo) now; latency hides under epi1 compute
    #pragma unroll
    for (int ctl = 0; ctl < 4; ++ctl)
        #pragma unroll
        for (int kt = 0; kt < 8; ++kt)
            bfr[ctl][kt] = *(const bf16x8*)(WoP + (((q * 4 + ctl) * 8 + kt) * 64 + lane) * 8);

    // epilogue 1: gated = sigmoid(T + bg) * weighted -> back into lx (swizzled)
    #pragma unroll
    for (int ctl = 0; ctl < 4; ++ctl) {
        int col = (q * 4 + ctl) * 16 + l15;
        float bgv = bg[col];
        int g0 = col >> 3, c7 = col & 7;
        #pragma unroll
        for (int rt = 0; rt < 4; ++rt) {
            #pragma unroll
            for (int j = 0; j < 4; ++j) {
                int row = rt * 16 + l4 * 4 + j;
                int i2 = (rowbase + row) & 511;
                float t = acc[rt][ctl][j] + bgv;
                float gv = 1.0f / (1.0f + __expf(-t));
                float gg = gv * weighted[i2 * 256 + col];
                lx[row * 256 + ((g0 ^ (row & 7)) << 3) + c7] = (bf16_t)gg;
            }
        }
    }
    __syncthreads();

    // stage 2: out = gated @ Wo
    #pragma unroll
    for (int rt = 0; rt < 4; ++rt)
        #pragma unroll
        for (int ctl = 0; ctl < 4; ++ctl) acc[rt][ctl] = (f32x4){0.f, 0.f, 0.f, 0.f};
    #pragma unroll
    for (int kt = 0; kt < 8; ++kt) {
        bf16x8 a[4];
        #pragma unroll
        for (int rt = 0; rt < 4; ++rt)
            a[rt] = *(bf16x8*)(lx + (rt * 16 + l15) * 256 + ((kt * 4 + l4) ^ swb) * 8);
        #pragma unroll
        for (int ctl = 0; ctl < 4; ++ctl)
            #pragma unroll
            for (int rt = 0; rt < 4; ++rt)
                acc[rt][ctl] = __builtin_amdgcn_mfma_f32_16x16x32_bf16(a[rt], bfr[ctl][kt], acc[rt][ctl], 0, 0, 0);
    }
    // epilogue 2: + bo, * mask, store f32
    #pragma unroll
    for (int ctl = 0; ctl < 4; ++ctl) {
        int col = (q * 4 + ctl) * 16 + l15;
        float bov = bo[col];
        #pragma unroll
        for (int rt = 0; rt < 4; ++rt) {
            #pragma unroll
            for (int j = 0; j < 4; ++j) {
                int row = rt * 16 + l4 * 4 + j;
                int r = rowbase + row;
                out[(size_t)r * 256 + col] = (acc[rt][ctl][j] + bov) * mask[r];
            }
        }
    }
}

extern "C" void kernel_launch(void* const* d_in, const int* in_sizes, int n_in,
                              void* d_out, int out_size, void* d_ws, size_t ws_size,
                              hipStream_t stream) {
    const float* msa   = (const float*)d_in[0];
    const float* mask  = (const float*)d_in[1];
    const float* gamma = (const float*)d_in[2];
    const float* beta  = (const float*)d_in[3];
    const float* Wq    = (const float*)d_in[4];
    const float* Wk    = (const float*)d_in[5];
    const float* Wv    = (const float*)d_in[6];
    const float* Wg    = (const float*)d_in[7];
    const float* bg    = (const float*)d_in[8];
    const float* Wo    = (const float*)d_in[9];
    const float* bo    = (const float*)d_in[10];
    float* out = (float*)d_out;

    char* ws = (char*)d_ws;
    bf16_t* xln   = (bf16_t*)(ws);                     // 128 MB
    bf16_t* kv    = (bf16_t*)(ws + 134217728);         // 32 MB
    float*  Qp    = (float*)(ws + 167772160);          // 512 KB
    float*  wgt   = (float*)(ws + 168296448);          // 512 KB
    bf16_t* WgP   = (bf16_t*)(ws + 168820736);         // 128 KB
    bf16_t* WoP   = (bf16_t*)(ws + 168951808);         // 128 KB
    bf16_t* WKVP  = (bf16_t*)(ws + 169082880);         // 32 KB
    float*  Qpart = (float*)(ws + 169115648);          // 4 MB
    float*  Qcnt  = (float*)(ws + 173309952);          // 16 KB

    k_prep<<<576, 256, 0, stream>>>(Wg, Wo, Wk, Wv, WgP, WoP, WKVP);
    kA<<<4096, 256, 0, stream>>>(msa, mask, gamma, beta, xln, kv, WKVP, Qpart, Qcnt);
    kB<<<512, 256, 0, stream>>>(Qpart, Qcnt, Wq, Qp);
    kC<<<512, 256, 0, stream>>>(kv, mask, Qp, wgt);
    kD<<<4096, 256, 0, stream>>>(xln, WgP, WoP, bg, bo, wgt, mask, out);
}